// Round 7
// baseline (683.067 us; speedup 1.0000x reference)
//
#include <hip/hip_runtime.h>
#include <hip/hip_bf16.h>

// ---------------------------------------------------------------------------
// Fused 3-layer GRU (B*N=16384 seqs, T=20, HS=128) for MI355X / gfx950.
// R7: 512 threads = 8 waves/block (2 waves/SIMD for latency hiding); wave w
// owns h-columns [w*16, w*16+16). MFMA operands SWAPPED vs R6: A = weight
// fragment, B = h fragment (f16 A/B layouts are symmetric), so D rows = gate
// cols -> each lane holds 4 consecutive h-cols: b64 LDS h-writeback and
// float4 global stores in the epilogues.
// Weights pre-swizzled to fragment order (f16) in d_ws; layout unchanged.
// ---------------------------------------------------------------------------

typedef _Float16 half8 __attribute__((ext_vector_type(8)));
typedef _Float16 half4 __attribute__((ext_vector_type(4)));
typedef float floatx4 __attribute__((ext_vector_type(4)));

#define MFMA16(a, b, c) __builtin_amdgcn_mfma_f32_16x16x32_f16((a), (b), (c), 0, 0, 0)

static __device__ __forceinline__ float ldin(const void* p, long i, bool f32) {
    return f32 ? ((const float*)p)[i]
               : __bfloat162float(((const __hip_bfloat16*)p)[i]);
}

// fp32 data read as bf16 gives mantissa-half elements with random exponents;
// genuine bf16 N(0,1) stays in (1e-8,1e8) or ==0.
static __device__ __forceinline__ bool detect_f32(const void* peT, const void* x) {
    const __hip_bfloat16* a = (const __hip_bfloat16*)peT;
    const __hip_bfloat16* b = (const __hip_bfloat16*)x;
    bool weird = false;
    for (int i = 0; i < 20; i++) {
        float v = fabsf(__bfloat162float(a[i]));
        if (!(v == 0.0f || (v > 1e-8f && v < 1e8f))) weird = true;
    }
    for (int i = 0; i < 64; i++) {
        float v = fabsf(__bfloat162float(b[i]));
        if (!(v == 0.0f || (v > 1e-8f && v < 1e8f))) weird = true;
    }
    return weird;
}

static __device__ __forceinline__ float fsigm(float x) {
    x = fminf(fmaxf(x, -60.f), 60.f);
    float e = __builtin_amdgcn_exp2f(-1.442695041f * x);
    return __builtin_amdgcn_rcpf(1.0f + e);
}
static __device__ __forceinline__ float ftanh(float x) {
    x = fminf(fmaxf(x, -30.f), 30.f);
    float e = __builtin_amdgcn_exp2f(2.885390082f * x);  // exp(2x)
    return 1.0f - 2.0f * __builtin_amdgcn_rcpf(1.0f + e);
}

// ws fragment layout (each frag = 512 halfs = 64 lanes x 8): slot order
//   [0,288)   Whh   (3 layers x 96)   frag in layer: (ctile*3+g)*4+ks, ctile 0..7
//   [288,480) WihR  (2 layers x 96)   same formula
//   [480,528) Wih0  (48)              (ctile*3+g)*2+ks   (K=64)
//   [528,544) outW  (16)              otile*4+ks
__global__ __launch_bounds__(64) void prepack_kernel(
    const void* __restrict__ Whh,
    const void* __restrict__ WihR,
    const void* __restrict__ Wih0,
    const void* __restrict__ outW,
    const void* __restrict__ peT,
    const void* __restrict__ x,
    _Float16* __restrict__ ws)
{
    const bool f32 = detect_f32(peT, x);
    int fid  = blockIdx.x;
    int lane = threadIdx.x;
    int nlo = lane & 15, quad = lane >> 4;
    const void* src;
    long base;
    int row, k0, ldk;
    if (fid < 288) {
        int l = fid / 96, r = fid % 96;
        int ks = r & 3, q1 = r >> 2, g = q1 % 3, ctile = q1 / 3;
        row = g * 128 + ctile * 16 + nlo; k0 = ks * 32 + quad * 8; ldk = 128;
        src = Whh; base = (long)l * 384 * 128;
    } else if (fid < 480) {
        int f = fid - 288; int l = f / 96, r = f % 96;
        int ks = r & 3, q1 = r >> 2, g = q1 % 3, ctile = q1 / 3;
        row = g * 128 + ctile * 16 + nlo; k0 = ks * 32 + quad * 8; ldk = 128;
        src = WihR; base = (long)l * 384 * 128;
    } else if (fid < 528) {
        int r = fid - 480;
        int ks = r & 1, q1 = r >> 1, g = q1 % 3, ctile = q1 / 3;
        row = g * 128 + ctile * 16 + nlo; k0 = ks * 32 + quad * 8; ldk = 64;
        src = Wih0; base = 0;
    } else {
        int r = fid - 528; int ks = r & 3, ot = r >> 2;
        row = ot * 16 + nlo; k0 = ks * 32 + quad * 8; ldk = 128;
        src = outW; base = 0;
    }
    _Float16* d = ws + (long)fid * 512 + lane * 8;
#pragma unroll
    for (int j = 0; j < 8; j++)
        d[j] = (_Float16)ldin(src, base + (long)row * ldk + k0 + j, f32);
}

__global__ __launch_bounds__(512, 2) void rnn_fused(
    const void* __restrict__ x,
    const void* __restrict__ peA,
    const void* __restrict__ peT,
    const void* __restrict__ embW,
    const void* __restrict__ embB,
    const void* __restrict__ bih,
    const void* __restrict__ bhh,
    const void* __restrict__ outB,
    const _Float16* __restrict__ ws,
    float* __restrict__ out)
{
    __shared__ __align__(16) _Float16 hA[3][64][136];
    __shared__ __align__(16) _Float16 eA[64][72];
    __shared__ float emb0[64], emb1[64], embb[64];

    const bool f32 = detect_f32(peT, x);

    const int tid  = threadIdx.x;
    const int w    = tid >> 6;        // wave 0..7: owns h-cols [w*16, w*16+16)
    const int lane = tid & 63;
    const int nlo  = lane & 15;       // D col  = sequence-within-tile
    const int quad = lane >> 4;
    const int qk   = quad * 8;
    const int c4   = w * 16 + quad * 4;  // first of 4 gate-cols this lane owns
    const int m0   = blockIdx.x * 64;

    {
        _Float16* hz = &hA[0][0][0];
        for (int i = tid; i < 3 * 64 * 136; i += 512) hz[i] = (_Float16)0.f;
    }
    if (tid < 64) {
        emb0[tid] = ldin(embW, tid * 2 + 0, f32);
        emb1[tid] = ldin(embW, tid * 2 + 1, f32);
        embb[tid] = ldin(embB, tid, f32);
    }

    // per-lane gate biases as vec4 over the 4 owned cols (c4+rg)
    floatx4 bR[3], bZ[3], bNiV[3], bNhV[3];
#pragma unroll
    for (int l = 0; l < 3; l++)
#pragma unroll
        for (int rg = 0; rg < 4; rg++) {
            int c = c4 + rg;
            bR[l][rg]   = ldin(bih, l * 384 + c, f32) + ldin(bhh, l * 384 + c, f32);
            bZ[l][rg]   = ldin(bih, l * 384 + 128 + c, f32) + ldin(bhh, l * 384 + 128 + c, f32);
            bNiV[l][rg] = ldin(bih, l * 384 + 256 + c, f32);
            bNhV[l][rg] = ldin(bhh, l * 384 + 256 + c, f32);
        }

    // h state fp32: [layer][seq-tile][rg]; lane's seq = st*16+nlo, col = c4+rg
    float hold[3][4][4];
#pragma unroll
    for (int l = 0; l < 3; l++)
#pragma unroll
        for (int st = 0; st < 4; st++)
#pragma unroll
            for (int rg = 0; rg < 4; rg++) hold[l][st][rg] = 0.f;

    const int em = tid >> 3;          // embedding row (sequence) 0..63
    const int ej = (tid & 7) * 8;     // embedding col base
    const float peAg = ldin(peA, (m0 + em) & 7, f32);

    __syncthreads();

    for (int t = 0; t < 20; t++) {
        // ---- embedding: e = relu(embW @ (x+pe) + embb) -> eA (f16) ----
        {
            float x0 = ldin(x, ((long)(m0 + em) * 20 + t) * 2 + 0, f32);
            float x1 = ldin(x, ((long)(m0 + em) * 20 + t) * 2 + 1, f32);
            float pe = ldin(peT, t, f32) + peAg;
            float xp0 = x0 + pe, xp1 = x1 + pe;
#pragma unroll
            for (int jj = 0; jj < 8; jj++) {
                float e = fmaf(emb0[ej + jj], xp0, fmaf(emb1[ej + jj], xp1, embb[ej + jj]));
                eA[em][ej + jj] = (_Float16)fmaxf(e, 0.f);
            }
        }
        __syncthreads();

#pragma unroll
        for (int l = 0; l < 3; l++) {
            const int KGI = (l == 0) ? 2 : 4;

            // A-operand = weight fragments (t-invariant within step; L2-hot)
            half8 WR[4], WZ[4], WN[4];
#pragma unroll
            for (int ks = 0; ks < 4; ks++) {
                WR[ks] = *(const half8*)(ws + ((long)(l * 96 + ((w * 3 + 0) * 4 + ks))) * 512 + lane * 8);
                WZ[ks] = *(const half8*)(ws + ((long)(l * 96 + ((w * 3 + 1) * 4 + ks))) * 512 + lane * 8);
                WN[ks] = *(const half8*)(ws + ((long)(l * 96 + ((w * 3 + 2) * 4 + ks))) * 512 + lane * 8);
            }
            half8 UR[4], UZ[4], UN[4];
#pragma unroll
            for (int ks = 0; ks < 4; ks++) {
                if (ks < KGI) {
                    long fR = (l == 0) ? (480 + ((w * 3 + 0) * 2 + ks))
                                       : (288 + (l - 1) * 96 + ((w * 3 + 0) * 4 + ks));
                    long fZ = (l == 0) ? (480 + ((w * 3 + 1) * 2 + ks))
                                       : (288 + (l - 1) * 96 + ((w * 3 + 1) * 4 + ks));
                    long fN = (l == 0) ? (480 + ((w * 3 + 2) * 2 + ks))
                                       : (288 + (l - 1) * 96 + ((w * 3 + 2) * 4 + ks));
                    UR[ks] = *(const half8*)(ws + fR * 512 + lane * 8);
                    UZ[ks] = *(const half8*)(ws + fZ * 512 + lane * 8);
                    UN[ks] = *(const half8*)(ws + fN * 512 + lane * 8);
                }
            }

#pragma unroll
            for (int st = 0; st < 4; st++) {
                // B-operand = h / input fragments from LDS (b128 reads)
                const _Float16* hrow = &hA[l][st * 16 + nlo][0];
                half8 Bh[4];
#pragma unroll
                for (int ks = 0; ks < 4; ks++)
                    Bh[ks] = *(const half8*)(hrow + ks * 32 + qk);
                const _Float16* irow = (l == 0) ? &eA[st * 16 + nlo][0]
                                                : &hA[l - 1][st * 16 + nlo][0];
                half8 Bi[4];
#pragma unroll
                for (int ks = 0; ks < 4; ks++)
                    if (ks < KGI) Bi[ks] = *(const half8*)(irow + ks * 32 + qk);

                floatx4 aR = bR[l], aZ = bZ[l], aNi = bNiV[l], aNh = bNhV[l];
#pragma unroll
                for (int ks = 0; ks < 4; ks++) {
                    aR  = MFMA16(WR[ks], Bh[ks], aR);
                    aZ  = MFMA16(WZ[ks], Bh[ks], aZ);
                    aNh = MFMA16(WN[ks], Bh[ks], aNh);
                }
#pragma unroll
                for (int ks = 0; ks < 4; ks++) {
                    if (ks < KGI) {
                        aR  = MFMA16(UR[ks], Bi[ks], aR);
                        aZ  = MFMA16(UZ[ks], Bi[ks], aZ);
                        aNi = MFMA16(UN[ks], Bi[ks], aNi);
                    }
                }
#pragma unroll
                for (int rg = 0; rg < 4; rg++) {
                    float r = fsigm(aR[rg]);
                    float z = fsigm(aZ[rg]);
                    float n = ftanh(aNi[rg] + r * aNh[rg]);
                    float h = hold[l][st][rg];
                    hold[l][st][rg] = n + z * (h - n);
                }
            }
            __syncthreads();  // all waves done reading hA[l] / hA[l-1] / eA
            // write h_l(t): lane owns 4 consecutive cols -> single b64 store
#pragma unroll
            for (int st = 0; st < 4; st++) {
                half4 hv;
#pragma unroll
                for (int rg = 0; rg < 4; rg++) hv[rg] = (_Float16)hold[l][st][rg];
                *(half4*)&hA[l][st * 16 + nlo][c4] = hv;
            }
            __syncthreads();  // hA[l] visible to layer l+1 / next step
        }
    }

    // ---- epilogue 1: out = h3(T) @ outW^T + out_b (fp32, float4 stores) ----
    if (w < 4) {           // o-tile = w (64 outputs = 4 tiles)
        half8 Ao[4];
#pragma unroll
        for (int ks = 0; ks < 4; ks++)
            Ao[ks] = *(const half8*)(ws + ((long)(528 + w * 4 + ks)) * 512 + lane * 8);
        floatx4 ob;
#pragma unroll
        for (int rg = 0; rg < 4; rg++) ob[rg] = ldin(outB, c4 + rg, f32);
#pragma unroll
        for (int st = 0; st < 4; st++) {
            const _Float16* hrow = &hA[2][st * 16 + nlo][0];
            floatx4 acc = ob;
#pragma unroll
            for (int ks = 0; ks < 4; ks++) {
                half8 b = *(const half8*)(hrow + ks * 32 + qk);
                acc = MFMA16(Ao[ks], b, acc);
            }
            *(floatx4*)&out[(long)(m0 + st * 16 + nlo) * 64 + c4] = acc;
        }
    }

    // ---- epilogue 2: hidden finals (seq % 8 == 7), float4 stores ----
    if ((nlo & 7) == 7) {
#pragma unroll
        for (int l = 0; l < 3; l++)
#pragma unroll
            for (int st = 0; st < 4; st++) {
                int m = m0 + st * 16 + nlo;
                long idx = 1048576L + ((long)l * 2048 + (m >> 3)) * 128 + c4;
                floatx4 v;
#pragma unroll
                for (int rg = 0; rg < 4; rg++) v[rg] = hold[l][st][rg];
                *(floatx4*)&out[idx] = v;
            }
    }
}

extern "C" void kernel_launch(void* const* d_in, const int* in_sizes, int n_in,
                              void* d_out, int out_size, void* d_ws, size_t ws_size,
                              hipStream_t stream)
{
    int ix = 0, ipeA = 1, ipeT = 2, iembW = 3, iembB = 4, iWih0 = 5, iWihR = 6,
        iWhh = 7, ibih = 8, ibhh = 9, ioutW = 10, ioutB = 11;
    int f64 = -1, s64 = -1, f1152 = -1, s1152 = -1;
    for (int i = 0; i < n_in; i++) {
        int s = in_sizes[i];
        if      (s == 655360) ix = i;
        else if (s == 8)      ipeA = i;
        else if (s == 20)     ipeT = i;
        else if (s == 128)    iembW = i;
        else if (s == 24576)  iWih0 = i;
        else if (s == 98304)  iWihR = i;
        else if (s == 147456) iWhh = i;
        else if (s == 8192)   ioutW = i;
        else if (s == 64)     { if (f64 < 0) f64 = i; else s64 = i; }
        else if (s == 1152)   { if (f1152 < 0) f1152 = i; else s1152 = i; }
    }
    if (f64 >= 0)   { iembB = f64;  ioutB = (s64  >= 0 ? s64  : f64); }
    if (f1152 >= 0) { ibih = f1152; ibhh = (s1152 >= 0 ? s1152 : f1152); }

    _Float16* ws = (_Float16*)d_ws;           // 544 frags * 1KB = 557056 B
    float* out = (float*)d_out;

    hipLaunchKernelGGL(prepack_kernel, dim3(544), dim3(64), 0, stream,
                       d_in[iWhh], d_in[iWihR], d_in[iWih0], d_in[ioutW],
                       d_in[ipeT], d_in[ix], ws);
    hipLaunchKernelGGL(rnn_fused, dim3(256), dim3(512), 0, stream,
                       d_in[ix], d_in[ipeA], d_in[ipeT], d_in[iembW], d_in[iembB],
                       d_in[ibih], d_in[ibhh], d_in[ioutB], ws, out);
}

// Round 8
// 668.610 us; speedup vs baseline: 1.0216x; 1.0216x over previous
//
#include <hip/hip_runtime.h>
#include <hip/hip_bf16.h>

// ---------------------------------------------------------------------------
// Fused 3-layer GRU (B*N=16384 seqs, T=20, HS=128) for MI355X / gfx950.
// R8: 32 seqs/block, 256 threads (4 waves), grid 512 -> 2 independent
// blocks/CU to hide barrier-phase latency (R7 evidence: time independent of
// traffic; 1 block/CU exposed every L2/LDS latency on the critical path).
// Wave w covers gate-cols [w*32, w*32+32) via ct in {0,1}; A-operand = weight
// frag, B-operand = h frag; lane owns 4 consecutive cols (b64 writeback).
// h state f16 in LDS only (no fp32 reg state), double-buffered -> 4 barriers/t.
// Biases in LDS. VGPR forced <=128 via __launch_bounds__(256,2).
// ---------------------------------------------------------------------------

typedef _Float16 half8 __attribute__((ext_vector_type(8)));
typedef _Float16 half4 __attribute__((ext_vector_type(4)));
typedef float floatx4 __attribute__((ext_vector_type(4)));

#define MFMA16(a, b, c) __builtin_amdgcn_mfma_f32_16x16x32_f16((a), (b), (c), 0, 0, 0)

static __device__ __forceinline__ float ldin(const void* p, long i, bool f32) {
    return f32 ? ((const float*)p)[i]
               : __bfloat162float(((const __hip_bfloat16*)p)[i]);
}

// fp32 data read as bf16 gives mantissa-half elements with random exponents;
// genuine bf16 N(0,1) stays in (1e-8,1e8) or ==0.
static __device__ __forceinline__ bool detect_f32(const void* peT, const void* x) {
    const __hip_bfloat16* a = (const __hip_bfloat16*)peT;
    const __hip_bfloat16* b = (const __hip_bfloat16*)x;
    bool weird = false;
    for (int i = 0; i < 20; i++) {
        float v = fabsf(__bfloat162float(a[i]));
        if (!(v == 0.0f || (v > 1e-8f && v < 1e8f))) weird = true;
    }
    for (int i = 0; i < 64; i++) {
        float v = fabsf(__bfloat162float(b[i]));
        if (!(v == 0.0f || (v > 1e-8f && v < 1e8f))) weird = true;
    }
    return weird;
}

static __device__ __forceinline__ float fsigm(float x) {
    x = fminf(fmaxf(x, -60.f), 60.f);
    float e = __builtin_amdgcn_exp2f(-1.442695041f * x);
    return __builtin_amdgcn_rcpf(1.0f + e);
}
static __device__ __forceinline__ float ftanh(float x) {
    x = fminf(fmaxf(x, -30.f), 30.f);
    float e = __builtin_amdgcn_exp2f(2.885390082f * x);  // exp(2x)
    return 1.0f - 2.0f * __builtin_amdgcn_rcpf(1.0f + e);
}

// ws fragment layout (each frag = 512 halfs = 64 lanes x 8): slot order
//   [0,288)   Whh   (3 layers x 96)   frag in layer: (ctile*3+g)*4+ks, ctile 0..7
//   [288,480) WihR  (2 layers x 96)   same formula
//   [480,528) Wih0  (48)              (ctile*3+g)*2+ks   (K=64)
//   [528,544) outW  (16)              otile*4+ks
__global__ __launch_bounds__(64) void prepack_kernel(
    const void* __restrict__ Whh,
    const void* __restrict__ WihR,
    const void* __restrict__ Wih0,
    const void* __restrict__ outW,
    const void* __restrict__ peT,
    const void* __restrict__ x,
    _Float16* __restrict__ ws)
{
    const bool f32 = detect_f32(peT, x);
    int fid  = blockIdx.x;
    int lane = threadIdx.x;
    int nlo = lane & 15, quad = lane >> 4;
    const void* src;
    long base;
    int row, k0, ldk;
    if (fid < 288) {
        int l = fid / 96, r = fid % 96;
        int ks = r & 3, q1 = r >> 2, g = q1 % 3, ctile = q1 / 3;
        row = g * 128 + ctile * 16 + nlo; k0 = ks * 32 + quad * 8; ldk = 128;
        src = Whh; base = (long)l * 384 * 128;
    } else if (fid < 480) {
        int f = fid - 288; int l = f / 96, r = f % 96;
        int ks = r & 3, q1 = r >> 2, g = q1 % 3, ctile = q1 / 3;
        row = g * 128 + ctile * 16 + nlo; k0 = ks * 32 + quad * 8; ldk = 128;
        src = WihR; base = (long)l * 384 * 128;
    } else if (fid < 528) {
        int r = fid - 480;
        int ks = r & 1, q1 = r >> 1, g = q1 % 3, ctile = q1 / 3;
        row = g * 128 + ctile * 16 + nlo; k0 = ks * 32 + quad * 8; ldk = 64;
        src = Wih0; base = 0;
    } else {
        int r = fid - 528; int ks = r & 3, ot = r >> 2;
        row = ot * 16 + nlo; k0 = ks * 32 + quad * 8; ldk = 128;
        src = outW; base = 0;
    }
    _Float16* d = ws + (long)fid * 512 + lane * 8;
#pragma unroll
    for (int j = 0; j < 8; j++)
        d[j] = (_Float16)ldin(src, base + (long)row * ldk + k0 + j, f32);
}

__global__ __launch_bounds__(256, 2) void rnn_fused(
    const void* __restrict__ x,
    const void* __restrict__ peA,
    const void* __restrict__ peT,
    const void* __restrict__ embW,
    const void* __restrict__ embB,
    const void* __restrict__ bih,
    const void* __restrict__ bhh,
    const void* __restrict__ outB,
    const _Float16* __restrict__ ws,
    float* __restrict__ out)
{
    // hA double-buffered: [layer][buf][seq][col+pad]
    __shared__ __align__(16) _Float16 hA[3][2][32][136];
    __shared__ __align__(16) _Float16 eA[32][72];
    __shared__ float emb0[64], emb1[64], embb[64];
    __shared__ float biasS[1536];   // [l][gate RZ Ni Nh][c]

    const bool f32 = detect_f32(peT, x);

    const int tid  = threadIdx.x;
    const int w    = tid >> 6;        // wave 0..3: gate-cols [w*32, w*32+32)
    const int lane = tid & 63;
    const int nlo  = lane & 15;       // D col = seq-within-tile
    const int quad = lane >> 4;
    const int qk   = quad * 8;
    const int m0   = blockIdx.x * 32;

    for (int i = tid; i < 3 * 2 * 32 * 136; i += 256)
        (&hA[0][0][0][0])[i] = (_Float16)0.f;
    if (tid < 64) {
        emb0[tid] = ldin(embW, tid * 2 + 0, f32);
        emb1[tid] = ldin(embW, tid * 2 + 1, f32);
        embb[tid] = ldin(embB, tid, f32);
    }
    for (int idx = tid; idx < 1536; idx += 256) {
        int l = idx >> 9, r = idx & 511, g = r >> 7, c = r & 127;
        float v;
        if      (g == 0) v = ldin(bih, l * 384 + c, f32)       + ldin(bhh, l * 384 + c, f32);
        else if (g == 1) v = ldin(bih, l * 384 + 128 + c, f32) + ldin(bhh, l * 384 + 128 + c, f32);
        else if (g == 2) v = ldin(bih, l * 384 + 256 + c, f32);
        else             v = ldin(bhh, l * 384 + 256 + c, f32);
        biasS[idx] = v;
    }

    const int em = tid >> 3;          // embedding seq 0..31
    const int ej = (tid & 7) * 8;     // embedding col base
    const float peAg = ldin(peA, (m0 + em) & 7, f32);

    __syncthreads();

    for (int t = 0; t < 20; t++) {
        const int p = t & 1, q = 1 - p;   // read h_{t-1} from p, write h_t to q

        // ---- embedding: e = relu(embW @ (x+pe) + embb) -> eA (f16) ----
        {
            float x0 = ldin(x, ((long)(m0 + em) * 20 + t) * 2 + 0, f32);
            float x1 = ldin(x, ((long)(m0 + em) * 20 + t) * 2 + 1, f32);
            float pe = ldin(peT, t, f32) + peAg;
            float xp0 = x0 + pe, xp1 = x1 + pe;
#pragma unroll
            for (int jj = 0; jj < 8; jj++) {
                float e = fmaf(emb0[ej + jj], xp0, fmaf(emb1[ej + jj], xp1, embb[ej + jj]));
                eA[em][ej + jj] = (_Float16)fmaxf(e, 0.f);
            }
        }
        __syncthreads();   // A: eA(t) ready; h writes of t-1 visible

#pragma unroll
        for (int l = 0; l < 3; l++) {
            const int KGI = (l == 0) ? 2 : 4;
#pragma unroll
            for (int ct = 0; ct < 2; ct++) {
                const int ctile = w * 2 + ct;
                const int c4 = ctile * 16 + quad * 4;  // first of lane's 4 cols

                // B-operand fragments (h_{t-1} from buf p; input from buf q / eA)
                half8 Bh[2][4], Bi[2][4];
                half4 hOld[2];
#pragma unroll
                for (int st = 0; st < 2; st++) {
                    const _Float16* hrow = &hA[l][p][st * 16 + nlo][0];
#pragma unroll
                    for (int ks = 0; ks < 4; ks++)
                        Bh[st][ks] = *(const half8*)(hrow + ks * 32 + qk);
                    const _Float16* irow = (l == 0) ? &eA[st * 16 + nlo][0]
                                                    : &hA[l - 1][q][st * 16 + nlo][0];
#pragma unroll
                    for (int ks = 0; ks < 4; ks++)
                        if (ks < KGI) Bi[st][ks] = *(const half8*)(irow + ks * 32 + qk);
                    hOld[st] = *(const half4*)&hA[l][p][st * 16 + nlo][c4];
                }

                // acc[0]=R, acc[1]=Z, acc[2]=Ni, acc[3]=Nh, per seq-tile
                floatx4 acc[4][2];
#pragma unroll
                for (int g = 0; g < 4; g++) {
                    floatx4 b = *(const floatx4*)&biasS[(l * 4 + g) * 128 + c4];
                    acc[g][0] = b; acc[g][1] = b;
                }
                // gh: gates R,Z,N(h) from Whh frags (each W frag -> 2 MFMAs)
#pragma unroll
                for (int g = 0; g < 3; g++) {
                    const int ai = (g == 2) ? 3 : g;
#pragma unroll
                    for (int ks = 0; ks < 4; ks++) {
                        half8 W = *(const half8*)(ws +
                            ((long)(l * 96 + (ctile * 3 + g) * 4 + ks)) * 512 + lane * 8);
                        acc[ai][0] = MFMA16(W, Bh[0][ks], acc[ai][0]);
                        acc[ai][1] = MFMA16(W, Bh[1][ks], acc[ai][1]);
                    }
                }
                // gi: gates R,Z,N(i) from Wih frags
#pragma unroll
                for (int g = 0; g < 3; g++) {
#pragma unroll
                    for (int ks = 0; ks < 4; ks++) {
                        if (ks < KGI) {
                            long f = (l == 0) ? (480 + ((ctile * 3 + g) * 2 + ks))
                                              : (288 + (l - 1) * 96 + ((ctile * 3 + g) * 4 + ks));
                            half8 U = *(const half8*)(ws + f * 512 + lane * 8);
                            acc[g][0] = MFMA16(U, Bi[0][ks], acc[g][0]);
                            acc[g][1] = MFMA16(U, Bi[1][ks], acc[g][1]);
                        }
                    }
                }
                // nonlinearity + f16 writeback to buf q (no hazard: readers use p)
#pragma unroll
                for (int st = 0; st < 2; st++) {
                    half4 hnew;
#pragma unroll
                    for (int rg = 0; rg < 4; rg++) {
                        float r = fsigm(acc[0][st][rg]);
                        float z = fsigm(acc[1][st][rg]);
                        float n = ftanh(acc[2][st][rg] + r * acc[3][st][rg]);
                        float ho = (float)hOld[st][rg];
                        hnew[rg] = (_Float16)(n + z * (ho - n));
                    }
                    *(half4*)&hA[l][q][st * 16 + nlo][c4] = hnew;
                }
            }
            __syncthreads();   // B_l: hA[l][q] ready for layer l+1 (or next t)
        }
    }

    // final h_T for all layers is in buf (19+1)&1 = 0
    // ---- epilogue 1: out = h3(T) @ outW^T + out_b (fp32 float4 stores) ----
    {
        half8 Ao[4];
#pragma unroll
        for (int ks = 0; ks < 4; ks++)
            Ao[ks] = *(const half8*)(ws + ((long)(528 + w * 4 + ks)) * 512 + lane * 8);
        floatx4 ob;
#pragma unroll
        for (int rg = 0; rg < 4; rg++) ob[rg] = ldin(outB, w * 16 + quad * 4 + rg, f32);
#pragma unroll
        for (int st = 0; st < 2; st++) {
            const _Float16* hrow = &hA[2][0][st * 16 + nlo][0];
            floatx4 acc = ob;
#pragma unroll
            for (int ks = 0; ks < 4; ks++) {
                half8 b = *(const half8*)(hrow + ks * 32 + qk);
                acc = MFMA16(Ao[ks], b, acc);
            }
            *(floatx4*)&out[(long)(m0 + st * 16 + nlo) * 64 + w * 16 + quad * 4] = acc;
        }
    }

    // ---- epilogue 2: hidden finals (seq % 8 == 7), float4 stores ----
    if ((nlo & 7) == 7) {
#pragma unroll
        for (int l = 0; l < 3; l++)
#pragma unroll
            for (int st = 0; st < 2; st++)
#pragma unroll
                for (int ct = 0; ct < 2; ct++) {
                    int m = m0 + st * 16 + nlo;
                    int c4 = w * 32 + ct * 16 + quad * 4;
                    floatx4 v;
#pragma unroll
                    for (int rg = 0; rg < 4; rg++)
                        v[rg] = (float)hA[l][0][st * 16 + nlo][c4 + rg];
                    *(floatx4*)&out[1048576L + ((long)l * 2048 + (m >> 3)) * 128 + c4] = v;
                }
    }
}

extern "C" void kernel_launch(void* const* d_in, const int* in_sizes, int n_in,
                              void* d_out, int out_size, void* d_ws, size_t ws_size,
                              hipStream_t stream)
{
    int ix = 0, ipeA = 1, ipeT = 2, iembW = 3, iembB = 4, iWih0 = 5, iWihR = 6,
        iWhh = 7, ibih = 8, ibhh = 9, ioutW = 10, ioutB = 11;
    int f64 = -1, s64 = -1, f1152 = -1, s1152 = -1;
    for (int i = 0; i < n_in; i++) {
        int s = in_sizes[i];
        if      (s == 655360) ix = i;
        else if (s == 8)      ipeA = i;
        else if (s == 20)     ipeT = i;
        else if (s == 128)    iembW = i;
        else if (s == 24576)  iWih0 = i;
        else if (s == 98304)  iWihR = i;
        else if (s == 147456) iWhh = i;
        else if (s == 8192)   ioutW = i;
        else if (s == 64)     { if (f64 < 0) f64 = i; else s64 = i; }
        else if (s == 1152)   { if (f1152 < 0) f1152 = i; else s1152 = i; }
    }
    if (f64 >= 0)   { iembB = f64;  ioutB = (s64  >= 0 ? s64  : f64); }
    if (f1152 >= 0) { ibih = f1152; ibhh = (s1152 >= 0 ? s1152 : f1152); }

    _Float16* ws = (_Float16*)d_ws;           // 544 frags * 1KB = 557056 B
    float* out = (float*)d_out;

    hipLaunchKernelGGL(prepack_kernel, dim3(544), dim3(64), 0, stream,
                       d_in[iWhh], d_in[iWihR], d_in[iWih0], d_in[ioutW],
                       d_in[ipeT], d_in[ix], ws);
    hipLaunchKernelGGL(rnn_fused, dim3(512), dim3(256), 0, stream,
                       d_in[ix], d_in[ipeA], d_in[ipeT], d_in[iembW], d_in[iembB],
                       d_in[ibih], d_in[ibhh], d_in[ioutB], ws, out);
}

// Round 9
// 484.036 us; speedup vs baseline: 1.4112x; 1.3813x over previous
//
#include <hip/hip_runtime.h>
#include <hip/hip_bf16.h>

// ---------------------------------------------------------------------------
// Fused 3-layer GRU (B*N=16384 seqs, T=20, HS=128) for MI355X / gfx950.
// R9: LAYER-WAVEFRONT pipeline. Block = 64 seqs, 512 threads (8 waves):
//   waves 0-1 -> layer 0 at t=s-1, waves 2-3 -> layer 1 at t=s-2,
//   waves 4-5 -> layer 2 at t=s-3, waves 6-7 -> embedding e(t=s).
// 23 phases, ONE barrier each (vs 60 steps / 80 barriers in R6-R8).
// Per-layer h double-buffered in LDS (f16); wave-in-layer W owns h-cols
// [W*64, W*64+64) = ctiles W*4..W*4+3. A-op = weight frag, B-op = h frag.
// Weights pre-swizzled (f16) in d_ws; prepack unchanged from R8.
// ---------------------------------------------------------------------------

typedef _Float16 half8 __attribute__((ext_vector_type(8)));
typedef _Float16 half4 __attribute__((ext_vector_type(4)));
typedef float floatx4 __attribute__((ext_vector_type(4)));

#define MFMA16(a, b, c) __builtin_amdgcn_mfma_f32_16x16x32_f16((a), (b), (c), 0, 0, 0)

static __device__ __forceinline__ float ldin(const void* p, long i, bool f32) {
    return f32 ? ((const float*)p)[i]
               : __bfloat162float(((const __hip_bfloat16*)p)[i]);
}

static __device__ __forceinline__ bool detect_f32(const void* peT, const void* x) {
    const __hip_bfloat16* a = (const __hip_bfloat16*)peT;
    const __hip_bfloat16* b = (const __hip_bfloat16*)x;
    bool weird = false;
    for (int i = 0; i < 20; i++) {
        float v = fabsf(__bfloat162float(a[i]));
        if (!(v == 0.0f || (v > 1e-8f && v < 1e8f))) weird = true;
    }
    for (int i = 0; i < 64; i++) {
        float v = fabsf(__bfloat162float(b[i]));
        if (!(v == 0.0f || (v > 1e-8f && v < 1e8f))) weird = true;
    }
    return weird;
}

static __device__ __forceinline__ float fsigm(float x) {
    x = fminf(fmaxf(x, -60.f), 60.f);
    float e = __builtin_amdgcn_exp2f(-1.442695041f * x);
    return __builtin_amdgcn_rcpf(1.0f + e);
}
static __device__ __forceinline__ float ftanh(float x) {
    x = fminf(fmaxf(x, -30.f), 30.f);
    float e = __builtin_amdgcn_exp2f(2.885390082f * x);  // exp(2x)
    return 1.0f - 2.0f * __builtin_amdgcn_rcpf(1.0f + e);
}

// ws fragment layout (each frag = 512 halfs = 64 lanes x 8): slot order
//   [0,288)   Whh   (3 layers x 96)   frag in layer: (ctile*3+g)*4+ks, ctile 0..7
//   [288,480) WihR  (2 layers x 96)   same formula
//   [480,528) Wih0  (48)              (ctile*3+g)*2+ks   (K=64)
//   [528,544) outW  (16)              otile*4+ks
__global__ __launch_bounds__(64) void prepack_kernel(
    const void* __restrict__ Whh,
    const void* __restrict__ WihR,
    const void* __restrict__ Wih0,
    const void* __restrict__ outW,
    const void* __restrict__ peT,
    const void* __restrict__ x,
    _Float16* __restrict__ ws)
{
    const bool f32 = detect_f32(peT, x);
    int fid  = blockIdx.x;
    int lane = threadIdx.x;
    int nlo = lane & 15, quad = lane >> 4;
    const void* src;
    long base;
    int row, k0, ldk;
    if (fid < 288) {
        int l = fid / 96, r = fid % 96;
        int ks = r & 3, q1 = r >> 2, g = q1 % 3, ctile = q1 / 3;
        row = g * 128 + ctile * 16 + nlo; k0 = ks * 32 + quad * 8; ldk = 128;
        src = Whh; base = (long)l * 384 * 128;
    } else if (fid < 480) {
        int f = fid - 288; int l = f / 96, r = f % 96;
        int ks = r & 3, q1 = r >> 2, g = q1 % 3, ctile = q1 / 3;
        row = g * 128 + ctile * 16 + nlo; k0 = ks * 32 + quad * 8; ldk = 128;
        src = WihR; base = (long)l * 384 * 128;
    } else if (fid < 528) {
        int r = fid - 480;
        int ks = r & 1, q1 = r >> 1, g = q1 % 3, ctile = q1 / 3;
        row = g * 128 + ctile * 16 + nlo; k0 = ks * 32 + quad * 8; ldk = 64;
        src = Wih0; base = 0;
    } else {
        int r = fid - 528; int ks = r & 3, ot = r >> 2;
        row = ot * 16 + nlo; k0 = ks * 32 + quad * 8; ldk = 128;
        src = outW; base = 0;
    }
    _Float16* d = ws + (long)fid * 512 + lane * 8;
#pragma unroll
    for (int j = 0; j < 8; j++)
        d[j] = (_Float16)ldin(src, base + (long)row * ldk + k0 + j, f32);
}

__global__ __launch_bounds__(512, 2) void rnn_fused(
    const void* __restrict__ x,
    const void* __restrict__ peA,
    const void* __restrict__ peT,
    const void* __restrict__ embW,
    const void* __restrict__ embB,
    const void* __restrict__ bih,
    const void* __restrict__ bhh,
    const void* __restrict__ outB,
    const _Float16* __restrict__ ws,
    float* __restrict__ out)
{
    // h per layer, double-buffered by t parity: [l][buf][seq][col+pad]
    __shared__ __align__(16) _Float16 hA[3][2][64][136];
    __shared__ __align__(16) _Float16 eA[2][64][72];
    __shared__ float emb0[64], emb1[64], embb[64];
    __shared__ float biasS[1536];   // [l][R,Z,Ni,Nh][128]

    const bool f32 = detect_f32(peT, x);

    const int tid  = threadIdx.x;
    const int w    = tid >> 6;
    const int lane = tid & 63;
    const int nlo  = lane & 15;     // D col = seq-within-tile
    const int quad = lane >> 4;
    const int qk   = quad * 8;
    const int m0   = blockIdx.x * 64;

    for (int i = tid; i < 3 * 2 * 64 * 136; i += 512)
        (&hA[0][0][0][0])[i] = (_Float16)0.f;
    if (tid < 64) {
        emb0[tid] = ldin(embW, tid * 2 + 0, f32);
        emb1[tid] = ldin(embW, tid * 2 + 1, f32);
        embb[tid] = ldin(embB, tid, f32);
    }
    for (int idx = tid; idx < 1536; idx += 512) {
        int l = idx >> 9, r = idx & 511, g = r >> 7, c = r & 127;
        float v;
        if      (g == 0) v = ldin(bih, l * 384 + c, f32)       + ldin(bhh, l * 384 + c, f32);
        else if (g == 1) v = ldin(bih, l * 384 + 128 + c, f32) + ldin(bhh, l * 384 + 128 + c, f32);
        else if (g == 2) v = ldin(bih, l * 384 + 256 + c, f32);
        else             v = ldin(bhh, l * 384 + 256 + c, f32);
        biasS[idx] = v;
    }
    __syncthreads();

#pragma unroll 1
    for (int s = 0; s < 23; s++) {
        if (w >= 6) {
            // ---- embedding waves: e(t=s) -> eA[s&1] ----
            if (s < 20) {
                int idx  = tid - 384;         // 0..127
                int seq  = idx & 63;
                int half = idx >> 6;          // 0..1 -> cols [half*32, +32)
                float x0 = ldin(x, ((long)(m0 + seq) * 20 + s) * 2 + 0, f32);
                float x1 = ldin(x, ((long)(m0 + seq) * 20 + s) * 2 + 1, f32);
                float pe = ldin(peT, s, f32) + ldin(peA, (m0 + seq) & 7, f32);
                float xp0 = x0 + pe, xp1 = x1 + pe;
                _Float16* erow = &eA[s & 1][seq][half * 32];
                const int cb = half * 32;
#pragma unroll
                for (int j = 0; j < 32; j++) {
                    float e = fmaf(emb0[cb + j], xp0, fmaf(emb1[cb + j], xp1, embb[cb + j]));
                    erow[j] = (_Float16)fmaxf(e, 0.f);
                }
            }
        } else {
            // ---- layer waves: layer l at t = s-1-l ----
            const int l = w >> 1;           // 0..2
            const int W = w & 1;            // wave-in-layer: h-cols [W*64, +64)
            const int t = s - 1 - l;
            if (t >= 0 && t < 20) {
                const int p = (t + 1) & 1;  // h(t-1) buf
                const int q = t & 1;        // h(t) write buf
                const int KGI = (l == 0) ? 2 : 4;
                const _Float16* inBase = (l == 0) ? &eA[t & 1][0][0]
                                                  : &hA[l - 1][t & 1][0][0];
                const int inStride = (l == 0) ? 72 : 136;

                // resident B-op h fragments (full K=128, all 4 seq-tiles)
                half8 Bh[4][4];
#pragma unroll
                for (int rt = 0; rt < 4; rt++)
#pragma unroll
                    for (int ks = 0; ks < 4; ks++)
                        Bh[rt][ks] = *(const half8*)&hA[l][p][rt * 16 + nlo][ks * 32 + qk];

#pragma unroll
                for (int ct = 0; ct < 4; ct++) {
                    const int c8 = W * 4 + ct;          // ctile 0..7 within gate
                    const int c4 = c8 * 16 + quad * 4;  // lane's first h-col

                    floatx4 acc[4][4];                  // [R,Z,Ni,Nh][rt]
#pragma unroll
                    for (int g = 0; g < 4; g++) {
                        floatx4 b = *(const floatx4*)&biasS[(l * 4 + g) * 128 + c4];
#pragma unroll
                        for (int rt = 0; rt < 4; rt++) acc[g][rt] = b;
                    }
                    // gh: h(t-1) @ Whh^T
#pragma unroll
                    for (int g = 0; g < 3; g++) {
                        const int ai = (g == 2) ? 3 : g;
#pragma unroll
                        for (int ks = 0; ks < 4; ks++) {
                            half8 Wf = *(const half8*)(ws +
                                ((long)(l * 96 + (c8 * 3 + g) * 4 + ks)) * 512 + lane * 8);
#pragma unroll
                            for (int rt = 0; rt < 4; rt++)
                                acc[ai][rt] = MFMA16(Wf, Bh[rt][ks], acc[ai][rt]);
                        }
                    }
                    // gi: input(t) @ Wih^T   (input = e for l0, ys_{l-1} else)
                    for (int ks = 0; ks < KGI; ks++) {
                        half8 Bi[4];
#pragma unroll
                        for (int rt = 0; rt < 4; rt++)
                            Bi[rt] = *(const half8*)(inBase +
                                     (rt * 16 + nlo) * inStride + ks * 32 + qk);
#pragma unroll
                        for (int g = 0; g < 3; g++) {
                            long f = (l == 0) ? (long)(480 + (c8 * 3 + g) * 2 + ks)
                                              : (long)(288 + (l - 1) * 96 + (c8 * 3 + g) * 4 + ks);
                            half8 Uf = *(const half8*)(ws + f * 512 + lane * 8);
#pragma unroll
                            for (int rt = 0; rt < 4; rt++)
                                acc[g][rt] = MFMA16(Uf, Bi[rt], acc[g][rt]);
                        }
                    }
                    // nonlinearity + f16 writeback (b64) to buf q
#pragma unroll
                    for (int rt = 0; rt < 4; rt++) {
                        half4 ho = *(const half4*)&hA[l][p][rt * 16 + nlo][c4];
                        half4 hn;
#pragma unroll
                        for (int rg = 0; rg < 4; rg++) {
                            float r = fsigm(acc[0][rt][rg]);
                            float z = fsigm(acc[1][rt][rg]);
                            float n = ftanh(acc[2][rt][rg] + r * acc[3][rt][rg]);
                            hn[rg] = (_Float16)(n + z * ((float)ho[rg] - n));
                        }
                        *(half4*)&hA[l][q][rt * 16 + nlo][c4] = hn;
                    }
                }
            }
        }
        __syncthreads();   // single barrier per phase
    }

    // ---- epilogue 1: out = h3(19) @ outW^T + out_b ; h3(19) in buf 1 ----
    {
        const int otile = w & 3;
        const int rtb   = (w >> 2) * 2;
        half8 Ao[4];
#pragma unroll
        for (int ks = 0; ks < 4; ks++)
            Ao[ks] = *(const half8*)(ws + ((long)(528 + otile * 4 + ks)) * 512 + lane * 8);
        floatx4 ob;
#pragma unroll
        for (int rg = 0; rg < 4; rg++) ob[rg] = ldin(outB, otile * 16 + quad * 4 + rg, f32);
#pragma unroll
        for (int rr = 0; rr < 2; rr++) {
            const int rt = rtb + rr;
            floatx4 acc = ob;
#pragma unroll
            for (int ks = 0; ks < 4; ks++) {
                half8 b = *(const half8*)&hA[2][1][rt * 16 + nlo][ks * 32 + qk];
                acc = MFMA16(Ao[ks], b, acc);
            }
            *(floatx4*)&out[(long)(m0 + rt * 16 + nlo) * 64 + otile * 16 + quad * 4] = acc;
        }
    }

    // ---- epilogue 2: hidden finals (seq % 8 == 7), h_l(19) in buf 1 ----
    for (int idx = tid; idx < 3 * 8 * 128; idx += 512) {
        int l = idx >> 10, r = idx & 1023, si = r >> 7, k = r & 127;
        int sq = si * 8 + 7;
        long m = m0 + sq;
        out[1048576L + ((long)l * 2048 + (m >> 3)) * 128 + k] =
            (float)hA[l][1][sq][k];
    }
}

extern "C" void kernel_launch(void* const* d_in, const int* in_sizes, int n_in,
                              void* d_out, int out_size, void* d_ws, size_t ws_size,
                              hipStream_t stream)
{
    int ix = 0, ipeA = 1, ipeT = 2, iembW = 3, iembB = 4, iWih0 = 5, iWihR = 6,
        iWhh = 7, ibih = 8, ibhh = 9, ioutW = 10, ioutB = 11;
    int f64 = -1, s64 = -1, f1152 = -1, s1152 = -1;
    for (int i = 0; i < n_in; i++) {
        int s = in_sizes[i];
        if      (s == 655360) ix = i;
        else if (s == 8)      ipeA = i;
        else if (s == 20)     ipeT = i;
        else if (s == 128)    iembW = i;
        else if (s == 24576)  iWih0 = i;
        else if (s == 98304)  iWihR = i;
        else if (s == 147456) iWhh = i;
        else if (s == 8192)   ioutW = i;
        else if (s == 64)     { if (f64 < 0) f64 = i; else s64 = i; }
        else if (s == 1152)   { if (f1152 < 0) f1152 = i; else s1152 = i; }
    }
    if (f64 >= 0)   { iembB = f64;  ioutB = (s64  >= 0 ? s64  : f64); }
    if (f1152 >= 0) { ibih = f1152; ibhh = (s1152 >= 0 ? s1152 : f1152); }

    _Float16* ws = (_Float16*)d_ws;           // 544 frags * 1KB = 557056 B
    float* out = (float*)d_out;

    hipLaunchKernelGGL(prepack_kernel, dim3(544), dim3(64), 0, stream,
                       d_in[iWhh], d_in[iWihR], d_in[iWih0], d_in[ioutW],
                       d_in[ipeT], d_in[ix], ws);
    hipLaunchKernelGGL(rnn_fused, dim3(256), dim3(512), 0, stream,
                       d_in[ix], d_in[ipeA], d_in[ipeT], d_in[iembW], d_in[iembB],
                       d_in[ibih], d_in[ibhh], d_in[ioutB], ws, out);
}